// Round 4
// baseline (218.100 us; speedup 1.0000x reference)
//
#include <hip/hip_runtime.h>

typedef __attribute__((ext_vector_type(8)))  short short8;
typedef __attribute__((ext_vector_type(4)))  float f32x4;
typedef __attribute__((ext_vector_type(16))) float f32x16;

#define Bv 4
#define Sv 2048
#define Dv 1024
#define Hv 16
#define HDv 64

// workspace byte offsets
#define OFF_XB  (size_t)0           // X bf16      [8192][1024]  16MB
#define OFF_WC  (size_t)16777216    // Wcat bf16   [3072][1024]   6MB
#define OFF_M2  (size_t)23068672    // mask*log2e  [4][2048]     32KB
#define OFF_QB  (size_t)25165824    // Q bf16  [64][2048][64]    16MB (scaled by 0.125*log2e)
#define OFF_KB  (size_t)41943040    // K bf16  [64][2048][64]    16MB
#define OFF_VT  (size_t)58720256    // V^T bf16 [64][64][2048]   16MB

#define QSCALE 0.180336879f   /* 0.125 * log2(e) */
#define LOG2E  1.44269504f

__device__ __forceinline__ unsigned short f2bf(float f) {
    union { float f; unsigned u; } v; v.f = f;
    unsigned r = v.u + 0x7FFFu + ((v.u >> 16) & 1u);   // RNE
    return (unsigned short)(r >> 16);
}
__device__ __forceinline__ float f4get(const float4& v, int i) {
    return i == 0 ? v.x : i == 1 ? v.y : i == 2 ? v.z : v.w;
}

#define GLOAD16(gp, lp)                                                        \
    __builtin_amdgcn_global_load_lds(                                          \
        (const __attribute__((address_space(1))) void*)(gp),                   \
        (__attribute__((address_space(3))) void*)(lp), 16, 0, 0)

// ---------------------------------------------------------------------------
// fp32 -> bf16 convert: X, Wq|Wk|Wv -> Wcat; mask -> mask*log2e (fp32)
// ---------------------------------------------------------------------------
__global__ void convert_kernel(const float* __restrict__ X,
                               const float* __restrict__ Wq,
                               const float* __restrict__ Wk,
                               const float* __restrict__ Wv,
                               const float* __restrict__ mask,
                               unsigned short* __restrict__ Xb,
                               unsigned short* __restrict__ Wc,
                               float* __restrict__ M2) {
    size_t i = ((size_t)blockIdx.x * 256 + threadIdx.x) * 4;
    if (i < 8388608) {
        float4 v = *(const float4*)(X + i);
        ushort4 o; o.x = f2bf(v.x); o.y = f2bf(v.y); o.z = f2bf(v.z); o.w = f2bf(v.w);
        *(ushort4*)(Xb + i) = o;
    } else if (i < 11534336) {
        size_t j = i - 8388608;
        int which = (int)(j >> 20);
        size_t r = j & 1048575;
        const float* W = which == 0 ? Wq : which == 1 ? Wk : Wv;
        float4 v = *(const float4*)(W + r);
        ushort4 o; o.x = f2bf(v.x); o.y = f2bf(v.y); o.z = f2bf(v.z); o.w = f2bf(v.w);
        *(ushort4*)(Wc + j) = o;
    } else {
        size_t j = i - 11534336;   // 8192 mask floats
        float4 v = *(const float4*)(mask + j);
        v.x *= LOG2E; v.y *= LOG2E; v.z *= LOG2E; v.w *= LOG2E;
        *(float4*)(M2 + j) = v;
    }
}

// ---------------------------------------------------------------------------
// QKV projection GEMM: [8192 x 1024] x [3072 x 1024]^T + bias -> bf16.
// Fragment-linear LDS staging (zero bank conflicts), XCD-swizzled grid.
// Q scaled by 0.125*log2e; V written directly transposed [bh][d][s].
// ---------------------------------------------------------------------------
__global__ void qkv_gemm(const unsigned short* __restrict__ Xb,
                         const unsigned short* __restrict__ Wc,
                         const float* __restrict__ bq,
                         const float* __restrict__ bk,
                         const float* __restrict__ bv,
                         unsigned short* __restrict__ Qb,
                         unsigned short* __restrict__ Kb,
                         unsigned short* __restrict__ Vt) {
    __shared__ __align__(16) char sm[32768];
    char* As = sm;            // 16 chunks of 1KB: chunk(rb,ks) = (rb*2+ks)*1024
    char* Bs = sm + 16384;

    const int tid  = threadIdx.x;
    const int w    = tid >> 6, lane = tid & 63;
    const int l15  = lane & 15, g = lane >> 4;

    // XCD swizzle: each XCD gets an m-contiguous band (8 m-tiles x all 24 n)
    const int lin  = blockIdx.x + (blockIdx.y << 6);
    const int lin2 = (lin & 7) * 192 + (lin >> 3);
    const int m0   = (lin2 / 24) * 128;
    const int n0   = (lin2 % 24) * 128;

    const int wr   = (w >> 1) * 64, wc = (w & 1) * 64;

    // staging: wave w stages A row-blocks {2w,2w+1} x ks{0,1}, same for B.
    // global per-lane: row = rb*16 + l15, colbytes = ks*64 + g*16
    const size_t laneoff = (size_t)l15 * 2048 + g * 16;
    const char* gA0 = (const char*)Xb + ((size_t)m0 + 2 * w * 16) * 2048 + laneoff;
    const char* gB0 = (const char*)Wc + ((size_t)n0 + 2 * w * 16) * 2048 + laneoff;
    char* lA = As + (2 * w) * 2048;   // two chunks per rb: rb*2048
    char* lB = Bs + (2 * w) * 2048;

    f32x4 acc[4][4];
#pragma unroll
    for (int a = 0; a < 4; ++a)
#pragma unroll
        for (int b = 0; b < 4; ++b)
#pragma unroll
            for (int r = 0; r < 4; ++r) acc[a][b][r] = 0.f;

    const int rbA = (w >> 1) * 4;   // frag row-block base for this wave (A)
    const int rbB = (w & 1) * 4;

    for (int k0 = 0; k0 < 1024; k0 += 64) {
        __syncthreads();
#pragma unroll
        for (int i = 0; i < 2; ++i) {      // rb = 2w+i
#pragma unroll
            for (int ks = 0; ks < 2; ++ks) {
                GLOAD16(gA0 + i * 32768 + ks * 64 + k0 * 2, lA + i * 2048 + ks * 1024);
                GLOAD16(gB0 + i * 32768 + ks * 64 + k0 * 2, lB + i * 2048 + ks * 1024);
            }
        }
        __syncthreads();
#pragma unroll
        for (int ks = 0; ks < 2; ++ks) {
            short8 af[4], bf[4];
#pragma unroll
            for (int fm = 0; fm < 4; ++fm)
                af[fm] = *(const short8*)(As + ((rbA + fm) * 2 + ks) * 1024 + lane * 16);
#pragma unroll
            for (int fn = 0; fn < 4; ++fn)
                bf[fn] = *(const short8*)(Bs + ((rbB + fn) * 2 + ks) * 1024 + lane * 16);
#pragma unroll
            for (int fm = 0; fm < 4; ++fm)
#pragma unroll
                for (int fn = 0; fn < 4; ++fn)
                    acc[fm][fn] = __builtin_amdgcn_mfma_f32_16x16x32_bf16(
                        af[fm], bf[fn], acc[fm][fn], 0, 0, 0);
        }
    }

#pragma unroll
    for (int fn = 0; fn < 4; ++fn) {
        int ng = n0 + wc + fn * 16 + l15;
        int which = ng >> 10, nn = ng & 1023;
        const float* bias = which == 0 ? bq : which == 1 ? bk : bv;
        float osc = (which == 0) ? QSCALE : 1.0f;
        float bvv = bias[nn];
        int h = nn >> 6, d = nn & 63;
#pragma unroll
        for (int fm = 0; fm < 4; ++fm) {
            int m4 = m0 + wr + fm * 16 + 4 * g;     // 4 consecutive s rows
            int b = m4 >> 11, s4 = m4 & 2047;
            if (which == 2) {
                // V^T: pack 4 consecutive s as ushort4 at row (bh*64+d)
                ushort4 pk;
                pk.x = f2bf(acc[fm][fn][0] + bvv);
                pk.y = f2bf(acc[fm][fn][1] + bvv);
                pk.z = f2bf(acc[fm][fn][2] + bvv);
                pk.w = f2bf(acc[fm][fn][3] + bvv);
                *(ushort4*)(Vt + ((size_t)((b * 16 + h) * 64 + d)) * 2048 + s4) = pk;
            } else {
                unsigned short* Out = which == 0 ? Qb : Kb;
#pragma unroll
                for (int r = 0; r < 4; ++r)
                    Out[(size_t)((b * 16 + h) * 2048 + s4 + r) * 64 + d] =
                        f2bf((acc[fm][fn][r] + bvv) * osc);
            }
        }
    }
}

// ---------------------------------------------------------------------------
// Flash attention: 4 waves x 64 q-rows (qn=2) = 256-row q-tile, kv tiles of
// 64, double-buffered fragment-linear LDS (zero conflicts), swapped S^T/O^T
// MFMA, exp2-domain softmax, cvt_pk+permlane32_swap packing, defer-max.
// Grid: 512 blocks, bh = lin&63 (XCD-grouped: 8 bh per XCD, K/V L2-resident).
// ---------------------------------------------------------------------------
__global__ __launch_bounds__(256, 2) void attn_kernel(
    const unsigned short* __restrict__ Qg,
    const unsigned short* __restrict__ Kg,
    const unsigned short* __restrict__ Vt,
    const float* __restrict__ M2,
    float* __restrict__ out) {
    __shared__ __align__(16) char sm[32768];
    const int tid = threadIdx.x;
    const int w = tid >> 6, lane = tid & 63;
    const int l31 = lane & 31, g2 = lane >> 5;
    const int lin = blockIdx.x;
    const int bh = lin & 63, qt = lin >> 6;
    const int bb = bh >> 4, h = bh & 15;
    const int q0w = qt * 256 + w * 64;      // wave's q base (64 rows)
    const float* mrow = M2 + bb * 2048;

    // ---- staging pointers: wave w stages K chunks {2w,2w+1}, V chunks same.
    // chunk c: K: row cm*32+l31, colbytes ks*32 + g2*16  (cm=c>>2, ks=c&3)
    //          V: row dm*32+l31 (stride 4096B), colbytes ks*32 + g2*16
    const int c0 = 2 * w, c1 = 2 * w + 1;
    const char* KgB = (const char*)Kg + (size_t)bh * 2048 * 128;
    const char* VtB = (const char*)Vt + (size_t)bh * 64 * 4096;
    const char* pK0 = KgB + (c0 >> 2) * 4096 + (size_t)l31 * 128 + (c0 & 3) * 32 + g2 * 16;
    const char* pK1 = KgB + (c1 >> 2) * 4096 + (size_t)l31 * 128 + (c1 & 3) * 32 + g2 * 16;
    const char* pV0 = VtB + (c0 >> 2) * 131072 + (size_t)l31 * 4096 + (c0 & 3) * 32 + g2 * 16;
    const char* pV1 = VtB + (c1 >> 2) * 131072 + (size_t)l31 * 4096 + (c1 & 3) * 32 + g2 * 16;

    // Q fragments (B-operand of S^T), already scaled by 0.125*log2e
    short8 qf[2][4];
#pragma unroll
    for (int qn = 0; qn < 2; ++qn)
#pragma unroll
        for (int ks = 0; ks < 4; ++ks)
            qf[qn][ks] = *(const short8*)(Qg + (size_t)(bh * 2048 + q0w + qn * 32 + l31) * 64
                                          + ks * 16 + g2 * 8);

    f32x16 o[2][2];
#pragma unroll
    for (int dm = 0; dm < 2; ++dm)
#pragma unroll
        for (int qn = 0; qn < 2; ++qn)
#pragma unroll
            for (int r = 0; r < 16; ++r) o[dm][qn][r] = 0.f;
    float mN[2] = {-3e38f, -3e38f}, lN[2] = {0.f, 0.f};

    // prologue: stage tile 0 into buf 0
    {
        char* Kb = sm, *Vb = sm + 8192;
        GLOAD16(pK0, Kb + c0 * 1024); GLOAD16(pK1, Kb + c1 * 1024);
        GLOAD16(pV0, Vb + c0 * 1024); GLOAD16(pV1, Vb + c1 * 1024);
        pK0 += 8192; pK1 += 8192; pV0 += 128; pV1 += 128;
    }
    __syncthreads();

    const char* rd = sm + lane * 16;    // fragment read base (lane-linear)

    for (int t = 0; t < 32; ++t) {
        const int kv0 = t * 64;
        const int buf = t & 1;
        const char* Kr = rd + buf * 16384;
        const char* Vr = Kr + 8192;

        if (t + 1 < 32) {   // stage next tile into buf^1
            char* Kb = sm + (buf ^ 1) * 16384, *Vb = Kb + 8192;
            GLOAD16(pK0, Kb + c0 * 1024); GLOAD16(pK1, Kb + c1 * 1024);
            GLOAD16(pV0, Vb + c0 * 1024); GLOAD16(pV1, Vb + c1 * 1024);
            pK0 += 8192; pK1 += 8192; pV0 += 128; pV1 += 128;
        }

        // mask preload (L1-resident broadcast)
        float4 mkv[2][4];
#pragma unroll
        for (int cm = 0; cm < 2; ++cm)
#pragma unroll
            for (int rq = 0; rq < 4; ++rq)
                mkv[cm][rq] = *(const float4*)(mrow + kv0 + cm * 32 + rq * 8 + g2 * 4);

        // S^T = K * Q^T
        f32x16 st[2][2];
#pragma unroll
        for (int cm = 0; cm < 2; ++cm)
#pragma unroll
            for (int qn = 0; qn < 2; ++qn)
#pragma unroll
                for (int r = 0; r < 16; ++r) st[cm][qn][r] = 0.f;
#pragma unroll
        for (int ks = 0; ks < 4; ++ks) {
#pragma unroll
            for (int cm = 0; cm < 2; ++cm) {
                short8 kf = *(const short8*)(Kr + (cm * 4 + ks) * 1024);
#pragma unroll
                for (int qn = 0; qn < 2; ++qn)
                    st[cm][qn] = __builtin_amdgcn_mfma_f32_32x32x16_bf16(
                        kf, qf[qn][ks], st[cm][qn], 0, 0, 0);
            }
        }

        // V^T fragments for PV (reused by both qn)
        short8 vf[2][4];
#pragma unroll
        for (int dm = 0; dm < 2; ++dm)
#pragma unroll
            for (int ks = 0; ks < 4; ++ks)
                vf[dm][ks] = *(const short8*)(Vr + (dm * 4 + ks) * 1024);

#pragma unroll
        for (int qn = 0; qn < 2; ++qn) {
            // mask + row max   (key = kv0 + cm*32 + (r&3) + 8*(r>>2) + 4*g2)
            float tm = -3e38f;
#pragma unroll
            for (int cm = 0; cm < 2; ++cm)
#pragma unroll
                for (int rq = 0; rq < 4; ++rq)
#pragma unroll
                    for (int j = 0; j < 4; ++j) {
                        float mk = f4get(mkv[cm][rq], j);
                        float sv = st[cm][qn][rq * 4 + j];
                        sv = (mk >= 0.f) ? sv + mk : mk;
                        st[cm][qn][rq * 4 + j] = sv;
                        tm = fmaxf(tm, sv);
                    }
            tm = fmaxf(tm, __shfl_xor(tm, 32));

            // defer-max: rescale only when running max grows materially
            if (__any(tm > mN[qn] + 10.f)) {
                float mnew = fmaxf(mN[qn], tm);
                float ps;
                asm("v_exp_f32 %0, %1" : "=v"(ps) : "v"(mN[qn] - mnew));
                mN[qn] = mnew;
                lN[qn] *= ps;
#pragma unroll
                for (int dm = 0; dm < 2; ++dm)
#pragma unroll
                    for (int r = 0; r < 16; ++r) o[dm][qn][r] *= ps;
            }

            // P = 2^(S' - m), row sum
            float ts = 0.f;
#pragma unroll
            for (int cm = 0; cm < 2; ++cm)
#pragma unroll
                for (int r = 0; r < 16; ++r) {
                    float p;
                    asm("v_exp_f32 %0, %1" : "=v"(p) : "v"(st[cm][qn][r] - mN[qn]));
                    st[cm][qn][r] = p;
                    ts += p;
                }
            ts += __shfl_xor(ts, 32);
            lN[qn] += ts;

            // PV: O^T += V^T * P^T ; P^T B-frag via cvt_pk + permlane32_swap
#pragma unroll
            for (int ks = 0; ks < 4; ++ks) {
                const int cm = ks >> 1;
                const int b0 = 8 * (ks & 1);
                unsigned x0, x1, y0, y1;
                asm("v_cvt_pk_bf16_f32 %0, %1, %2" : "=v"(x0) : "v"(st[cm][qn][b0 + 0]), "v"(st[cm][qn][b0 + 1]));
                asm("v_cvt_pk_bf16_f32 %0, %1, %2" : "=v"(x1) : "v"(st[cm][qn][b0 + 2]), "v"(st[cm][qn][b0 + 3]));
                asm("v_cvt_pk_bf16_f32 %0, %1, %2" : "=v"(y0) : "v"(st[cm][qn][b0 + 4]), "v"(st[cm][qn][b0 + 5]));
                asm("v_cvt_pk_bf16_f32 %0, %1, %2" : "=v"(y1) : "v"(st[cm][qn][b0 + 6]), "v"(st[cm][qn][b0 + 7]));
                asm("v_permlane32_swap_b32 %0, %1" : "+v"(x0), "+v"(y0));
                asm("v_permlane32_swap_b32 %0, %1" : "+v"(x1), "+v"(y1));
                union { unsigned u[4]; short8 s; } pb;
                pb.u[0] = x0; pb.u[1] = x1; pb.u[2] = y0; pb.u[3] = y1;
#pragma unroll
                for (int dm = 0; dm < 2; ++dm)
                    o[dm][qn] = __builtin_amdgcn_mfma_f32_32x32x16_bf16(
                        vf[dm][ks], pb.s, o[dm][qn], 0, 0, 0);
            }
        }
        __syncthreads();   // next tile staged + this tile's LDS reads done
    }

    // epilogue: divide by l, write fp32 [B,S,D]
#pragma unroll
    for (int qn = 0; qn < 2; ++qn) {
        float inv = 1.f / lN[qn];
        int q = q0w + qn * 32 + l31;
#pragma unroll
        for (int dm = 0; dm < 2; ++dm)
#pragma unroll
            for (int rq = 0; rq < 4; ++rq) {
                float4 v;
                v.x = o[dm][qn][rq * 4 + 0] * inv;
                v.y = o[dm][qn][rq * 4 + 1] * inv;
                v.z = o[dm][qn][rq * 4 + 2] * inv;
                v.w = o[dm][qn][rq * 4 + 3] * inv;
                int d = dm * 32 + rq * 8 + g2 * 4;
                *(float4*)(out + (size_t)(bb * 2048 + q) * 1024 + h * 64 + d) = v;
            }
    }
}

extern "C" void kernel_launch(void* const* d_in, const int* in_sizes, int n_in,
                              void* d_out, int out_size, void* d_ws, size_t ws_size,
                              hipStream_t stream) {
    const float* X    = (const float*)d_in[0];
    const float* mask = (const float*)d_in[1];
    const float* Wq   = (const float*)d_in[2];
    const float* bq   = (const float*)d_in[3];
    const float* Wk   = (const float*)d_in[4];
    const float* bk   = (const float*)d_in[5];
    const float* Wv   = (const float*)d_in[6];
    const float* bv   = (const float*)d_in[7];
    float* out = (float*)d_out;

    char* ws = (char*)d_ws;
    unsigned short* Xb = (unsigned short*)(ws + OFF_XB);
    unsigned short* Wc = (unsigned short*)(ws + OFF_WC);
    float*          M2 = (float*)(ws + OFF_M2);
    unsigned short* Qb = (unsigned short*)(ws + OFF_QB);
    unsigned short* Kb = (unsigned short*)(ws + OFF_KB);
    unsigned short* Vt = (unsigned short*)(ws + OFF_VT);

    convert_kernel<<<11272, 256, 0, stream>>>(X, Wq, Wk, Wv, mask, Xb, Wc, M2);
    qkv_gemm<<<dim3(64, 24), 256, 0, stream>>>(Xb, Wc, bq, bk, bv, Qb, Kb, Vt);
    attn_kernel<<<512, 256, 0, stream>>>(Qb, Kb, Vt, M2, out);
}